// Round 7
// baseline (574.399 us; speedup 1.0000x reference)
//
#include <hip/hip_runtime.h>
#include <hip/hip_bf16.h>
#include <math.h>

// EncoderLayer_68186900791439 — graph transformer encoder layer on MI355X.
// Round 7: attn is LLC-BW bound (FETCH == 800k x (k+v bytes)). Shrink bytes:
// k stored fp8-e4m3 (q,v stay bf16). qkv layout per node (u16 units, stride
// 640 = 1280 B): [0,256) q bf16 | [256,384) k fp8 (256 B) | [384,640) v bf16.
// qkv_gemm restructured: block=128 rows computes all 896 cols (A read once).
// 7 dispatches: prep+LN1, hist, scan, scatter, qkv_gemm, attn(+LN2), ffn.

typedef unsigned short u16;
using short8 = __attribute__((ext_vector_type(8))) short;
using f32x4  = __attribute__((ext_vector_type(4))) float;
using f32x2  = __attribute__((ext_vector_type(2))) float;

__device__ __forceinline__ float bf2f(u16 u) {
    return __uint_as_float(((unsigned int)u) << 16);
}
__device__ __forceinline__ u16 f2bf(float f) {
    __hip_bfloat16 h = __float2bfloat16(f);
    return __builtin_bit_cast(u16, h);
}
__device__ __forceinline__ float bfe(short8 v, int j) {
    return bf2f((u16)v[j]);
}
// decode 4 packed fp8-e4m3 (one dword) -> 4 f32 (HW cvt, OCP on gfx950)
__device__ __forceinline__ void fp8x4_to_f32(int w, float* out) {
    f32x2 lo = __builtin_amdgcn_cvt_pk_f32_fp8(w, false);
    f32x2 hi = __builtin_amdgcn_cvt_pk_f32_fp8(w, true);
    out[0] = lo[0]; out[1] = lo[1]; out[2] = hi[0]; out[3] = hi[1];
}

// ============ Kernel A: prep weights + bias concat + LN1 + zero cnt ==========
__global__ __launch_bounds__(256) void fused_prep_ln(
    const float* __restrict__ x, const float* __restrict__ ln1g,
    const float* __restrict__ ln1b,
    const float* __restrict__ Wq, const float* __restrict__ Wk,
    const float* __restrict__ Wv, const float* __restrict__ Ws,
    const float* __restrict__ W1, const float* __restrict__ W2,
    const float* __restrict__ bq, const float* __restrict__ bk,
    const float* __restrict__ bv, const float* __restrict__ bs,
    u16* __restrict__ wt, float* __restrict__ bc,
    u16* __restrict__ y, int* __restrict__ cnt, int n)
{
    int gsz = gridDim.x * 256;
    int gtid = blockIdx.x * 256 + threadIdx.x;

    for (int i = gtid; i < 147456 + 896; i += gsz) {
        if (i < 147456) {
            const float* W; int N; int base;
            if      (i <  32768) { W = Wq; N = 256; base = 0; }
            else if (i <  65536) { W = Wk; N = 256; base = 32768; }
            else if (i <  98304) { W = Wv; N = 256; base = 65536; }
            else if (i < 114688) { W = Ws; N = 128; base = 98304; }
            else if (i < 131072) { W = W1; N = 128; base = 114688; }
            else                 { W = W2; N = 128; base = 131072; }
            int j = i - base;
            int nIdx = j >> 7, k = j & 127;
            wt[i] = f2bf(W[(size_t)k * N + nIdx]);
        } else {
            int j = i - 147456;
            float v;
            if      (j < 256) v = bq[j];
            else if (j < 512) v = bk[j - 256];
            else if (j < 768) v = bv[j - 512];
            else              v = bs[j - 768];
            bc[j] = v;
        }
    }
    for (int i = gtid; i < n; i += gsz) cnt[i] = 0;
    int lane = threadIdx.x & 63;
    int gw = gtid >> 6, nw = gsz >> 6;
    for (int row = gw; row < n; row += nw) {
        size_t base = (size_t)row * 128;
        float v0 = x[base + lane];
        float v1 = x[base + 64 + lane];
        float s1 = v0 + v1, s2 = v0 * v0 + v1 * v1;
        for (int o = 1; o <= 32; o <<= 1) {
            s1 += __shfl_xor(s1, o);
            s2 += __shfl_xor(s2, o);
        }
        float mu = s1 * (1.f / 128.f);
        float var = s2 * (1.f / 128.f) - mu * mu;
        float rstd = rsqrtf(var + 1e-5f);
        y[base + lane]      = f2bf((v0 - mu) * rstd * ln1g[lane] + ln1b[lane]);
        y[base + 64 + lane] = f2bf((v1 - mu) * rstd * ln1g[64 + lane] + ln1b[64 + lane]);
    }
}

// ============================ CSR build ====================================
__global__ __launch_bounds__(256) void hist_kernel(const int* __restrict__ dst,
                                                   int* __restrict__ cnt, int e) {
    int stride = gridDim.x * 256;
    for (int i = blockIdx.x * 256 + threadIdx.x; i < e; i += stride)
        atomicAdd(&cnt[dst[i]], 1);
}

__global__ __launch_bounds__(1024) void scan_kernel(
    const int* __restrict__ cnt, int* __restrict__ rowptr,
    int* __restrict__ cursor, int n, int e)
{
    __shared__ int sh[1024];
    int tid = threadIdx.x;
    int chunk = (n + 1023) / 1024;
    int lo = tid * chunk, hi = min(lo + chunk, n);
    int s = 0;
    for (int i = lo; i < hi; ++i) s += cnt[i];
    sh[tid] = s;
    __syncthreads();
    for (int o = 1; o < 1024; o <<= 1) {
        int add = (tid >= o) ? sh[tid - o] : 0;
        __syncthreads();
        sh[tid] += add;
        __syncthreads();
    }
    int run = sh[tid] - s;
    for (int i = lo; i < hi; ++i) {
        rowptr[i] = run;
        cursor[i] = run;
        run += cnt[i];
    }
    if (tid == 0) rowptr[n] = e;
}

__global__ __launch_bounds__(256) void scatter_kernel(const int* __restrict__ dst,
                                                      const int* __restrict__ src,
                                                      int* __restrict__ cursor,
                                                      int* __restrict__ esrc, int e) {
    int stride = gridDim.x * 256;
    for (int i = blockIdx.x * 256 + threadIdx.x; i < e; i += stride) {
        int p = atomicAdd(&cursor[dst[i]], 1);
        esrc[p] = src[i];
    }
}

// =============== MFMA GEMM: qkv+skip, block = 128 rows x ALL 896 cols =========
// A[n x 128] bf16 read ONCE per row (no blockIdx.y re-read). Wave = 32 rows;
// col-group loop streams B from L2. Outputs into mixed-layout qkv + f32 skip.
__global__ __launch_bounds__(256) void qkv_gemm(
    const u16* __restrict__ A, const u16* __restrict__ Bt,
    const float* __restrict__ bias, u16* __restrict__ qkv,
    float* __restrict__ skip, int n)
{
    int wid = threadIdx.x >> 6, lane = threadIdx.x & 63;
    int lm = lane & 15, quad = lane >> 4;
    int r0 = blockIdx.x * 128 + wid * 32;

    // Last block's A reads overrun n into the adjacent ws buffer — harmless,
    // rows >= n are never stored.
    const u16* aBase = A + (size_t)(r0 + lm) * 128 + quad * 8;
    short8 a0[4], a1[4];
#pragma unroll
    for (int kk = 0; kk < 4; ++kk) {
        a0[kk] = *(const short8*)(aBase + kk * 32);
        a1[kk] = *(const short8*)(aBase + 16 * 128 + kk * 32);
    }
    unsigned char* kout = (unsigned char*)qkv;

    for (int cg = 0; cg < 7; ++cg) {
        f32x4 acc0[8], acc1[8];
#pragma unroll
        for (int j = 0; j < 8; ++j) {
            acc0[j] = (f32x4){0.f, 0.f, 0.f, 0.f};
            acc1[j] = (f32x4){0.f, 0.f, 0.f, 0.f};
        }
#pragma unroll
        for (int kk = 0; kk < 4; ++kk) {
#pragma unroll
            for (int j = 0; j < 8; ++j) {
                short8 bj = *(const short8*)(Bt + (size_t)(cg * 128 + j * 16 + lm) * 128
                                             + quad * 8 + kk * 32);
                acc0[j] = __builtin_amdgcn_mfma_f32_16x16x32_bf16(a0[kk], bj, acc0[j], 0, 0, 0);
                acc1[j] = __builtin_amdgcn_mfma_f32_16x16x32_bf16(a1[kk], bj, acc1[j], 0, 0, 0);
            }
        }
#pragma unroll
        for (int j = 0; j < 8; ++j) {
            int col = cg * 128 + j * 16 + lm;
            float bv = bias[col];
#pragma unroll
            for (int rt = 0; rt < 2; ++rt) {
#pragma unroll
                for (int i2 = 0; i2 < 4; ++i2) {
                    int row = r0 + rt * 16 + quad * 4 + i2;
                    if (row >= n) continue;
                    float v = (rt ? acc1[j][i2] : acc0[j][i2]) + bv;
                    if (col < 256) {                       // q bf16
                        qkv[(size_t)row * 640 + col] = f2bf(v);
                    } else if (col < 512) {                // k fp8 e4m3
                        int w = __builtin_amdgcn_cvt_pk_fp8_f32(v, v, 0, false);
                        kout[(size_t)row * 1280 + 512 + (col - 256)] = (unsigned char)(w & 0xff);
                    } else if (col < 768) {                // v bf16
                        qkv[(size_t)row * 640 + (col - 128)] = f2bf(v);
                    } else {                               // skip f32
                        skip[(size_t)row * 128 + (col - 768)] = v;
                    }
                }
            }
        }
    }
}

// =============== Attention: wave per dst, 2 edge slots, fp8 k ================
// Lane layout: slot=lane>>5, head=(lane>>4)&1, sub=lane&15. Lane owns 8 cols.
// Per-edge fetch: k 256 B (fp8) + v 512 B (bf16). Epilogue: slot merge +
// head-mean + skip + residual (sx in place) + LayerNorm2 -> y.
__global__ __launch_bounds__(256) void attn_kernel(
    const u16* __restrict__ qkv, const int* __restrict__ rowptr,
    const int* __restrict__ esrc, const float* __restrict__ x,
    float* __restrict__ sx, const float* __restrict__ g2,
    const float* __restrict__ b2, u16* __restrict__ y, int n)
{
    int wid = threadIdx.x >> 6, lane = threadIdx.x & 63;
    int i = blockIdx.x * 4 + wid;
    if (i >= n) return;
    int slot = lane >> 5;
    int sub  = lane & 15;
    int colOff = ((lane >> 4) & 1) * 128 + sub * 8;

    short8 q8 = *(const short8*)(qkv + (size_t)i * 640 + colOff);
    float qf[8];
#pragma unroll
    for (int j = 0; j < 8; ++j) qf[j] = bfe(q8, j);

    int beg = rowptr[i], end = rowptr[i + 1];
    float m = -INFINITY, l = 0.f;
    float acc[8] = {};
    const float scale = 0.08838834764831845f;   // 1/sqrt(128)

    int t = beg + slot;
    for (; t + 2 < end; t += 4) {               // 2 edges per slot in flight
        int s0 = esrc[t], s1 = esrc[t + 2];
        const u16* n0 = qkv + (size_t)s0 * 640;
        const u16* n1 = qkv + (size_t)s1 * 640;
        uint2 kw0 = *(const uint2*)((const unsigned char*)(n0 + 256) + colOff);
        uint2 kw1 = *(const uint2*)((const unsigned char*)(n1 + 256) + colOff);
        short8 v0 = *(const short8*)(n0 + 384 + colOff);
        short8 v1 = *(const short8*)(n1 + 384 + colOff);
        float k0f[8], k1f[8];
        fp8x4_to_f32((int)kw0.x, k0f); fp8x4_to_f32((int)kw0.y, k0f + 4);
        fp8x4_to_f32((int)kw1.x, k1f); fp8x4_to_f32((int)kw1.y, k1f + 4);
        float d0 = 0.f, d1 = 0.f;
#pragma unroll
        for (int j = 0; j < 8; ++j) {
            d0 += qf[j] * k0f[j];
            d1 += qf[j] * k1f[j];
        }
#pragma unroll
        for (int o = 1; o <= 8; o <<= 1) {      // reduce over 16-lane group
            d0 += __shfl_xor(d0, o);
            d1 += __shfl_xor(d1, o);
        }
        float al0 = d0 * scale, al1 = d1 * scale;
        float nm = fmaxf(m, fmaxf(al0, al1));
        float sc = expf(m - nm);                 // m=-inf first iter -> 0
        float w0 = expf(al0 - nm), w1 = expf(al1 - nm);
        l = l * sc + w0 + w1;
#pragma unroll
        for (int j = 0; j < 8; ++j)
            acc[j] = acc[j] * sc + w0 * bfe(v0, j) + w1 * bfe(v1, j);
        m = nm;
    }
    if (t < end) {                               // slot tail: single edge
        int s0 = esrc[t];
        const u16* n0 = qkv + (size_t)s0 * 640;
        uint2 kw0 = *(const uint2*)((const unsigned char*)(n0 + 256) + colOff);
        short8 v0 = *(const short8*)(n0 + 384 + colOff);
        float k0f[8];
        fp8x4_to_f32((int)kw0.x, k0f); fp8x4_to_f32((int)kw0.y, k0f + 4);
        float d0 = 0.f;
#pragma unroll
        for (int j = 0; j < 8; ++j) d0 += qf[j] * k0f[j];
#pragma unroll
        for (int o = 1; o <= 8; o <<= 1) d0 += __shfl_xor(d0, o);
        float al0 = d0 * scale;
        float nm = fmaxf(m, al0);
        float sc = expf(m - nm);
        float w0 = expf(al0 - nm);
        l = l * sc + w0;
#pragma unroll
        for (int j = 0; j < 8; ++j) acc[j] = acc[j] * sc + w0 * bfe(v0, j);
        m = nm;
    }

    // merge the two slots (guard exp(-inf - -inf) for degree<2 nodes)
    float mo = __shfl_xor(m, 32);
    float lo = __shfl_xor(l, 32);
    float nm = fmaxf(m, mo);
    float scS = (m  > -INFINITY) ? expf(m - nm)  : 0.f;
    float scO = (mo > -INFINITY) ? expf(mo - nm) : 0.f;
    l = l * scS + lo * scO;
    float inv = (l > 0.f) ? (1.f / l) : 0.f;
#pragma unroll
    for (int j = 0; j < 8; ++j) {
        float other = __shfl_xor(acc[j], 32);
        acc[j] = (acc[j] * scS + other * scO) * inv;
        acc[j] = 0.5f * (acc[j] + __shfl_xor(acc[j], 16));  // head mean
    }

    if (lane < 16) {                             // lanes 0..15 hold the row
        size_t base = (size_t)i * 128 + sub * 8;
        float4 xv0 = *(const float4*)(x + base);
        float4 xv1 = *(const float4*)(x + base + 4);
        float4 sk0 = *(const float4*)(sx + base);
        float4 sk1 = *(const float4*)(sx + base + 4);
        float r[8];
        r[0] = xv0.x + sk0.x + acc[0]; r[1] = xv0.y + sk0.y + acc[1];
        r[2] = xv0.z + sk0.z + acc[2]; r[3] = xv0.w + sk0.w + acc[3];
        r[4] = xv1.x + sk1.x + acc[4]; r[5] = xv1.y + sk1.y + acc[5];
        r[6] = xv1.z + sk1.z + acc[6]; r[7] = xv1.w + sk1.w + acc[7];
        *(float4*)(sx + base)     = make_float4(r[0], r[1], r[2], r[3]);
        *(float4*)(sx + base + 4) = make_float4(r[4], r[5], r[6], r[7]);
        float s1 = 0.f, s2 = 0.f;
#pragma unroll
        for (int j = 0; j < 8; ++j) { s1 += r[j]; s2 += r[j] * r[j]; }
#pragma unroll
        for (int o = 1; o <= 8; o <<= 1) {
            s1 += __shfl_xor(s1, o);
            s2 += __shfl_xor(s2, o);
        }
        float mu = s1 * (1.f / 128.f);
        float var = s2 * (1.f / 128.f) - mu * mu;
        float rstd = rsqrtf(var + 1e-5f);
        short8 o8;
#pragma unroll
        for (int j = 0; j < 8; ++j)
            o8[j] = (short)f2bf((r[j] - mu) * rstd * g2[sub * 8 + j] + b2[sub * 8 + j]);
        *(short8*)(y + base) = o8;
    }
}

// =============== Fused FFN: out = x2 + gelu(y2@W1T+b1)@W2T+b2 ===============
__global__ __launch_bounds__(256) void ffn_kernel(
    const u16* __restrict__ y2, const u16* __restrict__ W1T,
    const float* __restrict__ b1, const u16* __restrict__ W2T,
    const float* __restrict__ b2, const float* __restrict__ x2,
    float* __restrict__ out, int n)
{
    __shared__ u16 t1[64 * 136];
    int wid = threadIdx.x >> 6, lane = threadIdx.x & 63;
    int lm = lane & 15, quad = lane >> 4;
    int r0 = blockIdx.x * 64 + wid * 16;

    const u16* aBase = y2 + (size_t)(r0 + lm) * 128 + quad * 8;
    f32x4 acc[8] = {};
#pragma unroll
    for (int kk = 0; kk < 128; kk += 32) {
        short8 a0 = *(const short8*)(aBase + kk);
#pragma unroll
        for (int j = 0; j < 8; ++j) {
            short8 bj = *(const short8*)(W1T + (size_t)(j * 16 + lm) * 128 + quad * 8 + kk);
            acc[j] = __builtin_amdgcn_mfma_f32_16x16x32_bf16(a0, bj, acc[j], 0, 0, 0);
        }
    }
#pragma unroll
    for (int j = 0; j < 8; ++j) {
        int col = j * 16 + lm;
        float bv = b1[col];
#pragma unroll
        for (int i2 = 0; i2 < 4; ++i2) {
            int rl = wid * 16 + quad * 4 + i2;
            float v = acc[j][i2] + bv;
            v = 0.5f * v * (1.f + erff(v * 0.70710678118654752f));
            t1[rl * 136 + col] = f2bf(v);
        }
    }
    __syncthreads();

    f32x4 acc2[8] = {};
#pragma unroll
    for (int kk = 0; kk < 128; kk += 32) {
        short8 a0 = *(const short8*)(t1 + (wid * 16 + lm) * 136 + quad * 8 + kk);
#pragma unroll
        for (int j = 0; j < 8; ++j) {
            short8 bj = *(const short8*)(W2T + (size_t)(j * 16 + lm) * 128 + quad * 8 + kk);
            acc2[j] = __builtin_amdgcn_mfma_f32_16x16x32_bf16(a0, bj, acc2[j], 0, 0, 0);
        }
    }
#pragma unroll
    for (int j = 0; j < 8; ++j) {
        int col = j * 16 + lm;
        float bv = b2[col];
#pragma unroll
        for (int i2 = 0; i2 < 4; ++i2) {
            int row = r0 + quad * 4 + i2;
            if (row >= n) continue;
            size_t ob = (size_t)row * 128 + col;
            out[ob] = acc2[j][i2] + bv + x2[ob];
        }
    }
}

extern "C" void kernel_launch(void* const* d_in, const int* in_sizes, int n_in,
                              void* d_out, int out_size, void* d_ws, size_t ws_size,
                              hipStream_t stream)
{
    const float* x    = (const float*)d_in[0];
    const int*   ei   = (const int*)d_in[1];

    int n = in_sizes[0] / 128;     // 50000
    int e = in_sizes[1] / 2;       // 800000
    const int* src  = ei;          // edge_index[0] (messages src -> dst)
    const int* dstp = ei + e;      // edge_index[1]

    char* w = (char*)d_ws;
    size_t off = 0;
    auto alloc = [&](size_t bytes) -> void* {
        void* p = w + off;
        off = (off + bytes + 255) & ~(size_t)255;
        return p;
    };
    u16*   y    = (u16*)alloc((size_t)n * 128 * 2);   // LN1 out, then LN2 out
    u16*   qkv  = (u16*)alloc((size_t)n * 640 * 2);   // q bf16 | k fp8 | v bf16
    float* sx   = (float*)alloc((size_t)n * 128 * 4); // skip, then x2 in-place
    u16*   wt   = (u16*)alloc((size_t)147456 * 2);
    float* bc   = (float*)alloc(896 * 4);
    int* cnt    = (int*)alloc((size_t)n * 4);
    int* cursor = (int*)alloc((size_t)n * 4);
    int* rowptr = (int*)alloc(((size_t)n + 1) * 4);
    int* esrc   = (int*)alloc((size_t)e * 4);

    int gr  = (n + 63) / 64;       // ffn row blocks
    int gq  = (n + 127) / 128;     // qkv row blocks

    fused_prep_ln<<<2048, 256, 0, stream>>>(
        x, (const float*)d_in[2], (const float*)d_in[3],
        (const float*)d_in[4], (const float*)d_in[6], (const float*)d_in[8],
        (const float*)d_in[10], (const float*)d_in[14], (const float*)d_in[16],
        (const float*)d_in[5], (const float*)d_in[7], (const float*)d_in[9],
        (const float*)d_in[11], wt, bc, y, cnt, n);
    hist_kernel<<<1024, 256, 0, stream>>>(dstp, cnt, e);
    scan_kernel<<<1, 1024, 0, stream>>>(cnt, rowptr, cursor, n, e);
    scatter_kernel<<<1024, 256, 0, stream>>>(dstp, src, cursor, esrc, e);
    qkv_gemm<<<gq, 256, 0, stream>>>(y, wt, bc, qkv, sx, n);
    attn_kernel<<<(n + 3) / 4, 256, 0, stream>>>(qkv, rowptr, esrc, x, sx,
                                                 (const float*)d_in[12],
                                                 (const float*)d_in[13], y, n);
    ffn_kernel<<<gr, 256, 0, stream>>>(y, wt + 114688, (const float*)d_in[15],
                                       wt + 131072, (const float*)d_in[17],
                                       sx, (float*)d_out, n);
}

// Round 8
// 537.447 us; speedup vs baseline: 1.0688x; 1.0688x over previous
//
#include <hip/hip_runtime.h>
#include <hip/hip_bf16.h>
#include <math.h>

// EncoderLayer_68186900791439 — graph transformer encoder layer on MI355X.
// Round 8: revert qkv_gemm to high-parallelism 2D grid (round-7 1D restructure
// was latency-bound: 391 blocks, occupancy 16%, MfmaUtil 3.5%). Keep fp8-k
// mixed qkv layout (stride 640 u16 = 1280 B: q bf16 | k fp8 | v bf16).
// 7 dispatches: prep+LN1, hist, scan, scatter, qkv_gemm, attn(+LN2), ffn.

typedef unsigned short u16;
using short8 = __attribute__((ext_vector_type(8))) short;
using f32x4  = __attribute__((ext_vector_type(4))) float;
using f32x2  = __attribute__((ext_vector_type(2))) float;

__device__ __forceinline__ float bf2f(u16 u) {
    return __uint_as_float(((unsigned int)u) << 16);
}
__device__ __forceinline__ u16 f2bf(float f) {
    __hip_bfloat16 h = __float2bfloat16(f);
    return __builtin_bit_cast(u16, h);
}
__device__ __forceinline__ float bfe(short8 v, int j) {
    return bf2f((u16)v[j]);
}
// decode 4 packed fp8-e4m3 (one dword) -> 4 f32 (HW cvt, OCP on gfx950)
__device__ __forceinline__ void fp8x4_to_f32(int w, float* out) {
    f32x2 lo = __builtin_amdgcn_cvt_pk_f32_fp8(w, false);
    f32x2 hi = __builtin_amdgcn_cvt_pk_f32_fp8(w, true);
    out[0] = lo[0]; out[1] = lo[1]; out[2] = hi[0]; out[3] = hi[1];
}

// ============ Kernel A: prep weights + bias concat + LN1 + zero cnt ==========
__global__ __launch_bounds__(256) void fused_prep_ln(
    const float* __restrict__ x, const float* __restrict__ ln1g,
    const float* __restrict__ ln1b,
    const float* __restrict__ Wq, const float* __restrict__ Wk,
    const float* __restrict__ Wv, const float* __restrict__ Ws,
    const float* __restrict__ W1, const float* __restrict__ W2,
    const float* __restrict__ bq, const float* __restrict__ bk,
    const float* __restrict__ bv, const float* __restrict__ bs,
    u16* __restrict__ wt, float* __restrict__ bc,
    u16* __restrict__ y, int* __restrict__ cnt, int n)
{
    int gsz = gridDim.x * 256;
    int gtid = blockIdx.x * 256 + threadIdx.x;

    for (int i = gtid; i < 147456 + 896; i += gsz) {
        if (i < 147456) {
            const float* W; int N; int base;
            if      (i <  32768) { W = Wq; N = 256; base = 0; }
            else if (i <  65536) { W = Wk; N = 256; base = 32768; }
            else if (i <  98304) { W = Wv; N = 256; base = 65536; }
            else if (i < 114688) { W = Ws; N = 128; base = 98304; }
            else if (i < 131072) { W = W1; N = 128; base = 114688; }
            else                 { W = W2; N = 128; base = 131072; }
            int j = i - base;
            int nIdx = j >> 7, k = j & 127;
            wt[i] = f2bf(W[(size_t)k * N + nIdx]);
        } else {
            int j = i - 147456;
            float v;
            if      (j < 256) v = bq[j];
            else if (j < 512) v = bk[j - 256];
            else if (j < 768) v = bv[j - 512];
            else              v = bs[j - 768];
            bc[j] = v;
        }
    }
    for (int i = gtid; i < n; i += gsz) cnt[i] = 0;
    int lane = threadIdx.x & 63;
    int gw = gtid >> 6, nw = gsz >> 6;
    for (int row = gw; row < n; row += nw) {
        size_t base = (size_t)row * 128;
        float v0 = x[base + lane];
        float v1 = x[base + 64 + lane];
        float s1 = v0 + v1, s2 = v0 * v0 + v1 * v1;
        for (int o = 1; o <= 32; o <<= 1) {
            s1 += __shfl_xor(s1, o);
            s2 += __shfl_xor(s2, o);
        }
        float mu = s1 * (1.f / 128.f);
        float var = s2 * (1.f / 128.f) - mu * mu;
        float rstd = rsqrtf(var + 1e-5f);
        y[base + lane]      = f2bf((v0 - mu) * rstd * ln1g[lane] + ln1b[lane]);
        y[base + 64 + lane] = f2bf((v1 - mu) * rstd * ln1g[64 + lane] + ln1b[64 + lane]);
    }
}

// ============================ CSR build ====================================
__global__ __launch_bounds__(256) void hist_kernel(const int* __restrict__ dst,
                                                   int* __restrict__ cnt, int e) {
    int stride = gridDim.x * 256;
    for (int i = blockIdx.x * 256 + threadIdx.x; i < e; i += stride)
        atomicAdd(&cnt[dst[i]], 1);
}

__global__ __launch_bounds__(1024) void scan_kernel(
    const int* __restrict__ cnt, int* __restrict__ rowptr,
    int* __restrict__ cursor, int n, int e)
{
    __shared__ int sh[1024];
    int tid = threadIdx.x;
    int chunk = (n + 1023) / 1024;
    int lo = tid * chunk, hi = min(lo + chunk, n);
    int s = 0;
    for (int i = lo; i < hi; ++i) s += cnt[i];
    sh[tid] = s;
    __syncthreads();
    for (int o = 1; o < 1024; o <<= 1) {
        int add = (tid >= o) ? sh[tid - o] : 0;
        __syncthreads();
        sh[tid] += add;
        __syncthreads();
    }
    int run = sh[tid] - s;
    for (int i = lo; i < hi; ++i) {
        rowptr[i] = run;
        cursor[i] = run;
        run += cnt[i];
    }
    if (tid == 0) rowptr[n] = e;
}

__global__ __launch_bounds__(256) void scatter_kernel(const int* __restrict__ dst,
                                                      const int* __restrict__ src,
                                                      int* __restrict__ cursor,
                                                      int* __restrict__ esrc, int e) {
    int stride = gridDim.x * 256;
    for (int i = blockIdx.x * 256 + threadIdx.x; i < e; i += stride) {
        int p = atomicAdd(&cursor[dst[i]], 1);
        esrc[p] = src[i];
    }
}

// =============== MFMA GEMM: qkv+skip — 2D grid, block 64 rows x 128 cols ======
// A[n x 128] bf16, Bt [896 x 128] bf16. 2x2 waves, wave = 32 rows x 64 cols.
// B tiles are tiny (0.3 MB total) and L2-resident; A re-read across gy is
// L2/LLC-cached — parallelism (5474 blocks) beats read-once (r7 lesson).
// Output: col<256 q bf16 | col<512 k fp8 | col<768 v bf16 | else skip f32.
__global__ __launch_bounds__(256) void qkv_gemm(
    const u16* __restrict__ A, const u16* __restrict__ Bt,
    const float* __restrict__ bias, u16* __restrict__ qkv,
    float* __restrict__ skip, int n)
{
    int wid = threadIdx.x >> 6, lane = threadIdx.x & 63;
    int wr = wid >> 1, wc = wid & 1;
    int r0 = blockIdx.x * 64 + wr * 32;
    int c0 = blockIdx.y * 128 + wc * 64;
    int lm = lane & 15, quad = lane >> 4;

    // Last row-block reads overrun n into the adjacent ws buffer — harmless,
    // rows >= n are never stored.
    const u16* aBase = A  + (size_t)(r0 + lm) * 128 + quad * 8;
    const u16* bBase = Bt + (size_t)(c0 + lm) * 128 + quad * 8;

    f32x4 acc[2][4] = {};
#pragma unroll
    for (int kk = 0; kk < 128; kk += 32) {
        short8 a0 = *(const short8*)(aBase + kk);
        short8 a1 = *(const short8*)(aBase + 16 * 128 + kk);
#pragma unroll
        for (int j = 0; j < 4; ++j) {
            short8 bj = *(const short8*)(bBase + (size_t)j * 16 * 128 + kk);
            acc[0][j] = __builtin_amdgcn_mfma_f32_16x16x32_bf16(a0, bj, acc[0][j], 0, 0, 0);
            acc[1][j] = __builtin_amdgcn_mfma_f32_16x16x32_bf16(a1, bj, acc[1][j], 0, 0, 0);
        }
    }
    unsigned char* kout = (unsigned char*)qkv;
#pragma unroll
    for (int j = 0; j < 4; ++j) {
        int col = c0 + j * 16 + lm;
        float bv = bias[col];
#pragma unroll
        for (int rt = 0; rt < 2; ++rt) {
#pragma unroll
            for (int i2 = 0; i2 < 4; ++i2) {
                int row = r0 + rt * 16 + quad * 4 + i2;
                if (row >= n) continue;
                float v = acc[rt][j][i2] + bv;
                if (col < 256) {                       // q bf16
                    qkv[(size_t)row * 640 + col] = f2bf(v);
                } else if (col < 512) {                // k fp8 e4m3
                    int w = __builtin_amdgcn_cvt_pk_fp8_f32(v, v, 0, false);
                    kout[(size_t)row * 1280 + 512 + (col - 256)] = (unsigned char)(w & 0xff);
                } else if (col < 768) {                // v bf16
                    qkv[(size_t)row * 640 + (col - 128)] = f2bf(v);
                } else {                               // skip f32
                    skip[(size_t)row * 128 + (col - 768)] = v;
                }
            }
        }
    }
}

// =============== Attention: wave per dst, 2 edge slots, fp8 k ================
// Lane layout: slot=lane>>5, head=(lane>>4)&1, sub=lane&15. Lane owns 8 cols.
// Per-edge fetch: k 256 B (fp8) + v 512 B (bf16). Epilogue: slot merge +
// head-mean + skip + residual (sx in place) + LayerNorm2 -> y.
__global__ __launch_bounds__(256) void attn_kernel(
    const u16* __restrict__ qkv, const int* __restrict__ rowptr,
    const int* __restrict__ esrc, const float* __restrict__ x,
    float* __restrict__ sx, const float* __restrict__ g2,
    const float* __restrict__ b2, u16* __restrict__ y, int n)
{
    int wid = threadIdx.x >> 6, lane = threadIdx.x & 63;
    int i = blockIdx.x * 4 + wid;
    if (i >= n) return;
    int slot = lane >> 5;
    int sub  = lane & 15;
    int colOff = ((lane >> 4) & 1) * 128 + sub * 8;

    short8 q8 = *(const short8*)(qkv + (size_t)i * 640 + colOff);
    float qf[8];
#pragma unroll
    for (int j = 0; j < 8; ++j) qf[j] = bfe(q8, j);

    int beg = rowptr[i], end = rowptr[i + 1];
    float m = -INFINITY, l = 0.f;
    float acc[8] = {};
    const float scale = 0.08838834764831845f;   // 1/sqrt(128)

    int t = beg + slot;
    for (; t + 2 < end; t += 4) {               // 2 edges per slot in flight
        int s0 = esrc[t], s1 = esrc[t + 2];
        const u16* n0 = qkv + (size_t)s0 * 640;
        const u16* n1 = qkv + (size_t)s1 * 640;
        uint2 kw0 = *(const uint2*)((const unsigned char*)(n0 + 256) + colOff);
        uint2 kw1 = *(const uint2*)((const unsigned char*)(n1 + 256) + colOff);
        short8 v0 = *(const short8*)(n0 + 384 + colOff);
        short8 v1 = *(const short8*)(n1 + 384 + colOff);
        float k0f[8], k1f[8];
        fp8x4_to_f32((int)kw0.x, k0f); fp8x4_to_f32((int)kw0.y, k0f + 4);
        fp8x4_to_f32((int)kw1.x, k1f); fp8x4_to_f32((int)kw1.y, k1f + 4);
        float d0 = 0.f, d1 = 0.f;
#pragma unroll
        for (int j = 0; j < 8; ++j) {
            d0 += qf[j] * k0f[j];
            d1 += qf[j] * k1f[j];
        }
#pragma unroll
        for (int o = 1; o <= 8; o <<= 1) {      // reduce over 16-lane group
            d0 += __shfl_xor(d0, o);
            d1 += __shfl_xor(d1, o);
        }
        float al0 = d0 * scale, al1 = d1 * scale;
        float nm = fmaxf(m, fmaxf(al0, al1));
        float sc = expf(m - nm);                 // m=-inf first iter -> 0
        float w0 = expf(al0 - nm), w1 = expf(al1 - nm);
        l = l * sc + w0 + w1;
#pragma unroll
        for (int j = 0; j < 8; ++j)
            acc[j] = acc[j] * sc + w0 * bfe(v0, j) + w1 * bfe(v1, j);
        m = nm;
    }
    if (t < end) {                               // slot tail: single edge
        int s0 = esrc[t];
        const u16* n0 = qkv + (size_t)s0 * 640;
        uint2 kw0 = *(const uint2*)((const unsigned char*)(n0 + 256) + colOff);
        short8 v0 = *(const short8*)(n0 + 384 + colOff);
        float k0f[8];
        fp8x4_to_f32((int)kw0.x, k0f); fp8x4_to_f32((int)kw0.y, k0f + 4);
        float d0 = 0.f;
#pragma unroll
        for (int j = 0; j < 8; ++j) d0 += qf[j] * k0f[j];
#pragma unroll
        for (int o = 1; o <= 8; o <<= 1) d0 += __shfl_xor(d0, o);
        float al0 = d0 * scale;
        float nm = fmaxf(m, al0);
        float sc = expf(m - nm);
        float w0 = expf(al0 - nm);
        l = l * sc + w0;
#pragma unroll
        for (int j = 0; j < 8; ++j) acc[j] = acc[j] * sc + w0 * bfe(v0, j);
        m = nm;
    }

    // merge the two slots (guard exp(-inf - -inf) for degree<2 nodes)
    float mo = __shfl_xor(m, 32);
    float lo = __shfl_xor(l, 32);
    float nm = fmaxf(m, mo);
    float scS = (m  > -INFINITY) ? expf(m - nm)  : 0.f;
    float scO = (mo > -INFINITY) ? expf(mo - nm) : 0.f;
    l = l * scS + lo * scO;
    float inv = (l > 0.f) ? (1.f / l) : 0.f;
#pragma unroll
    for (int j = 0; j < 8; ++j) {
        float other = __shfl_xor(acc[j], 32);
        acc[j] = (acc[j] * scS + other * scO) * inv;
        acc[j] = 0.5f * (acc[j] + __shfl_xor(acc[j], 16));  // head mean
    }

    if (lane < 16) {                             // lanes 0..15 hold the row
        size_t base = (size_t)i * 128 + sub * 8;
        float4 xv0 = *(const float4*)(x + base);
        float4 xv1 = *(const float4*)(x + base + 4);
        float4 sk0 = *(const float4*)(sx + base);
        float4 sk1 = *(const float4*)(sx + base + 4);
        float r[8];
        r[0] = xv0.x + sk0.x + acc[0]; r[1] = xv0.y + sk0.y + acc[1];
        r[2] = xv0.z + sk0.z + acc[2]; r[3] = xv0.w + sk0.w + acc[3];
        r[4] = xv1.x + sk1.x + acc[4]; r[5] = xv1.y + sk1.y + acc[5];
        r[6] = xv1.z + sk1.z + acc[6]; r[7] = xv1.w + sk1.w + acc[7];
        *(float4*)(sx + base)     = make_float4(r[0], r[1], r[2], r[3]);
        *(float4*)(sx + base + 4) = make_float4(r[4], r[5], r[6], r[7]);
        float s1 = 0.f, s2 = 0.f;
#pragma unroll
        for (int j = 0; j < 8; ++j) { s1 += r[j]; s2 += r[j] * r[j]; }
#pragma unroll
        for (int o = 1; o <= 8; o <<= 1) {
            s1 += __shfl_xor(s1, o);
            s2 += __shfl_xor(s2, o);
        }
        float mu = s1 * (1.f / 128.f);
        float var = s2 * (1.f / 128.f) - mu * mu;
        float rstd = rsqrtf(var + 1e-5f);
        short8 o8;
#pragma unroll
        for (int j = 0; j < 8; ++j)
            o8[j] = (short)f2bf((r[j] - mu) * rstd * g2[sub * 8 + j] + b2[sub * 8 + j]);
        *(short8*)(y + base) = o8;
    }
}

// =============== Fused FFN: out = x2 + gelu(y2@W1T+b1)@W2T+b2 ===============
__global__ __launch_bounds__(256) void ffn_kernel(
    const u16* __restrict__ y2, const u16* __restrict__ W1T,
    const float* __restrict__ b1, const u16* __restrict__ W2T,
    const float* __restrict__ b2, const float* __restrict__ x2,
    float* __restrict__ out, int n)
{
    __shared__ u16 t1[64 * 136];
    int wid = threadIdx.x >> 6, lane = threadIdx.x & 63;
    int lm = lane & 15, quad = lane >> 4;
    int r0 = blockIdx.x * 64 + wid * 16;

    const u16* aBase = y2 + (size_t)(r0 + lm) * 128 + quad * 8;
    f32x4 acc[8] = {};
#pragma unroll
    for (int kk = 0; kk < 128; kk += 32) {
        short8 a0 = *(const short8*)(aBase + kk);
#pragma unroll
        for (int j = 0; j < 8; ++j) {
            short8 bj = *(const short8*)(W1T + (size_t)(j * 16 + lm) * 128 + quad * 8 + kk);
            acc[j] = __builtin_amdgcn_mfma_f32_16x16x32_bf16(a0, bj, acc[j], 0, 0, 0);
        }
    }
#pragma unroll
    for (int j = 0; j < 8; ++j) {
        int col = j * 16 + lm;
        float bv = b1[col];
#pragma unroll
        for (int i2 = 0; i2 < 4; ++i2) {
            int rl = wid * 16 + quad * 4 + i2;
            float v = acc[j][i2] + bv;
            v = 0.5f * v * (1.f + erff(v * 0.70710678118654752f));
            t1[rl * 136 + col] = f2bf(v);
        }
    }
    __syncthreads();

    f32x4 acc2[8] = {};
#pragma unroll
    for (int kk = 0; kk < 128; kk += 32) {
        short8 a0 = *(const short8*)(t1 + (wid * 16 + lm) * 136 + quad * 8 + kk);
#pragma unroll
        for (int j = 0; j < 8; ++j) {
            short8 bj = *(const short8*)(W2T + (size_t)(j * 16 + lm) * 128 + quad * 8 + kk);
            acc2[j] = __builtin_amdgcn_mfma_f32_16x16x32_bf16(a0, bj, acc2[j], 0, 0, 0);
        }
    }
#pragma unroll
    for (int j = 0; j < 8; ++j) {
        int col = j * 16 + lm;
        float bv = b2[col];
#pragma unroll
        for (int i2 = 0; i2 < 4; ++i2) {
            int row = r0 + quad * 4 + i2;
            if (row >= n) continue;
            size_t ob = (size_t)row * 128 + col;
            out[ob] = acc2[j][i2] + bv + x2[ob];
        }
    }
}

extern "C" void kernel_launch(void* const* d_in, const int* in_sizes, int n_in,
                              void* d_out, int out_size, void* d_ws, size_t ws_size,
                              hipStream_t stream)
{
    const float* x    = (const float*)d_in[0];
    const int*   ei   = (const int*)d_in[1];

    int n = in_sizes[0] / 128;     // 50000
    int e = in_sizes[1] / 2;       // 800000
    const int* src  = ei;          // edge_index[0] (messages src -> dst)
    const int* dstp = ei + e;      // edge_index[1]

    char* w = (char*)d_ws;
    size_t off = 0;
    auto alloc = [&](size_t bytes) -> void* {
        void* p = w + off;
        off = (off + bytes + 255) & ~(size_t)255;
        return p;
    };
    u16*   y    = (u16*)alloc((size_t)n * 128 * 2);   // LN1 out, then LN2 out
    u16*   qkv  = (u16*)alloc((size_t)n * 640 * 2);   // q bf16 | k fp8 | v bf16
    float* sx   = (float*)alloc((size_t)n * 128 * 4); // skip, then x2 in-place
    u16*   wt   = (u16*)alloc((size_t)147456 * 2);
    float* bc   = (float*)alloc(896 * 4);
    int* cnt    = (int*)alloc((size_t)n * 4);
    int* cursor = (int*)alloc((size_t)n * 4);
    int* rowptr = (int*)alloc(((size_t)n + 1) * 4);
    int* esrc   = (int*)alloc((size_t)e * 4);

    int gr  = (n + 63) / 64;       // row blocks (qkv + ffn)

    fused_prep_ln<<<2048, 256, 0, stream>>>(
        x, (const float*)d_in[2], (const float*)d_in[3],
        (const float*)d_in[4], (const float*)d_in[6], (const float*)d_in[8],
        (const float*)d_in[10], (const float*)d_in[14], (const float*)d_in[16],
        (const float*)d_in[5], (const float*)d_in[7], (const float*)d_in[9],
        (const float*)d_in[11], wt, bc, y, cnt, n);
    hist_kernel<<<1024, 256, 0, stream>>>(dstp, cnt, e);
    scan_kernel<<<1, 1024, 0, stream>>>(cnt, rowptr, cursor, n, e);
    scatter_kernel<<<1024, 256, 0, stream>>>(dstp, src, cursor, esrc, e);
    qkv_gemm<<<dim3(gr, 7), 256, 0, stream>>>(y, wt, bc, qkv, sx, n);
    attn_kernel<<<(n + 3) / 4, 256, 0, stream>>>(qkv, rowptr, esrc, x, sx,
                                                 (const float*)d_in[12],
                                                 (const float*)d_in[13], y, n);
    ffn_kernel<<<gr, 256, 0, stream>>>(y, wt + 114688, (const float*)d_in[15],
                                       wt + 131072, (const float*)d_in[17],
                                       sx, (float*)d_out, n);
}

// Round 9
// 435.646 us; speedup vs baseline: 1.3185x; 1.2337x over previous
//
#include <hip/hip_runtime.h>
#include <hip/hip_bf16.h>
#include <math.h>

// EncoderLayer_68186900791439 — graph transformer encoder layer on MI355X.
// Round 9: single-block scan (114 us, 0.14% occupancy — r8 top dispatch) is
// replaced with the 3-kernel hierarchical chain (196-block sums, 1-block scan
// of partials, 196-block write). Everything else identical to round 8.
// 9 dispatches: prep+LN1, hist, scan x3, scatter, qkv_gemm, attn(+LN2), ffn.

typedef unsigned short u16;
using short8 = __attribute__((ext_vector_type(8))) short;
using f32x4  = __attribute__((ext_vector_type(4))) float;
using f32x2  = __attribute__((ext_vector_type(2))) float;

__device__ __forceinline__ float bf2f(u16 u) {
    return __uint_as_float(((unsigned int)u) << 16);
}
__device__ __forceinline__ u16 f2bf(float f) {
    __hip_bfloat16 h = __float2bfloat16(f);
    return __builtin_bit_cast(u16, h);
}
__device__ __forceinline__ float bfe(short8 v, int j) {
    return bf2f((u16)v[j]);
}
// decode 4 packed fp8-e4m3 (one dword) -> 4 f32 (HW cvt, OCP on gfx950)
__device__ __forceinline__ void fp8x4_to_f32(int w, float* out) {
    f32x2 lo = __builtin_amdgcn_cvt_pk_f32_fp8(w, false);
    f32x2 hi = __builtin_amdgcn_cvt_pk_f32_fp8(w, true);
    out[0] = lo[0]; out[1] = lo[1]; out[2] = hi[0]; out[3] = hi[1];
}

// ============ Kernel A: prep weights + bias concat + LN1 + zero cnt ==========
__global__ __launch_bounds__(256) void fused_prep_ln(
    const float* __restrict__ x, const float* __restrict__ ln1g,
    const float* __restrict__ ln1b,
    const float* __restrict__ Wq, const float* __restrict__ Wk,
    const float* __restrict__ Wv, const float* __restrict__ Ws,
    const float* __restrict__ W1, const float* __restrict__ W2,
    const float* __restrict__ bq, const float* __restrict__ bk,
    const float* __restrict__ bv, const float* __restrict__ bs,
    u16* __restrict__ wt, float* __restrict__ bc,
    u16* __restrict__ y, int* __restrict__ cnt, int n)
{
    int gsz = gridDim.x * 256;
    int gtid = blockIdx.x * 256 + threadIdx.x;

    for (int i = gtid; i < 147456 + 896; i += gsz) {
        if (i < 147456) {
            const float* W; int N; int base;
            if      (i <  32768) { W = Wq; N = 256; base = 0; }
            else if (i <  65536) { W = Wk; N = 256; base = 32768; }
            else if (i <  98304) { W = Wv; N = 256; base = 65536; }
            else if (i < 114688) { W = Ws; N = 128; base = 98304; }
            else if (i < 131072) { W = W1; N = 128; base = 114688; }
            else                 { W = W2; N = 128; base = 131072; }
            int j = i - base;
            int nIdx = j >> 7, k = j & 127;
            wt[i] = f2bf(W[(size_t)k * N + nIdx]);
        } else {
            int j = i - 147456;
            float v;
            if      (j < 256) v = bq[j];
            else if (j < 512) v = bk[j - 256];
            else if (j < 768) v = bv[j - 512];
            else              v = bs[j - 768];
            bc[j] = v;
        }
    }
    for (int i = gtid; i < n; i += gsz) cnt[i] = 0;
    int lane = threadIdx.x & 63;
    int gw = gtid >> 6, nw = gsz >> 6;
    for (int row = gw; row < n; row += nw) {
        size_t base = (size_t)row * 128;
        float v0 = x[base + lane];
        float v1 = x[base + 64 + lane];
        float s1 = v0 + v1, s2 = v0 * v0 + v1 * v1;
        for (int o = 1; o <= 32; o <<= 1) {
            s1 += __shfl_xor(s1, o);
            s2 += __shfl_xor(s2, o);
        }
        float mu = s1 * (1.f / 128.f);
        float var = s2 * (1.f / 128.f) - mu * mu;
        float rstd = rsqrtf(var + 1e-5f);
        y[base + lane]      = f2bf((v0 - mu) * rstd * ln1g[lane] + ln1b[lane]);
        y[base + 64 + lane] = f2bf((v1 - mu) * rstd * ln1g[64 + lane] + ln1b[64 + lane]);
    }
}

// ============================ CSR build ====================================
__global__ __launch_bounds__(256) void hist_kernel(const int* __restrict__ dst,
                                                   int* __restrict__ cnt, int e) {
    int stride = gridDim.x * 256;
    for (int i = blockIdx.x * 256 + threadIdx.x; i < e; i += stride)
        atomicAdd(&cnt[dst[i]], 1);
}

// 3-kernel hierarchical exclusive scan (r8 lesson: 1-block scan = 114 us on
// one CU; parallel chain is ~10x cheaper even with 2 extra launches).
__global__ __launch_bounds__(256) void scan_block_sum(const int* __restrict__ cnt,
                                                      int* __restrict__ bsum, int n) {
    __shared__ int s[256];
    int idx = blockIdx.x * 256 + threadIdx.x;
    s[threadIdx.x] = (idx < n) ? cnt[idx] : 0;
    __syncthreads();
    for (int o = 128; o > 0; o >>= 1) {
        if (threadIdx.x < o) s[threadIdx.x] += s[threadIdx.x + o];
        __syncthreads();
    }
    if (threadIdx.x == 0) bsum[blockIdx.x] = s[0];
}
__global__ __launch_bounds__(256) void scan_partials(const int* __restrict__ bsum,
                                                     int* __restrict__ bsumex, int nb) {
    __shared__ int s[256];
    int t = threadIdx.x;
    int v = (t < nb) ? bsum[t] : 0;
    s[t] = v;
    __syncthreads();
    for (int o = 1; o < 256; o <<= 1) {
        int add = (t >= o) ? s[t - o] : 0;
        __syncthreads();
        s[t] += add;
        __syncthreads();
    }
    bsumex[t] = s[t] - v;
}
__global__ __launch_bounds__(256) void scan_write(const int* __restrict__ cnt,
                                                  const int* __restrict__ bsumex,
                                                  int* __restrict__ rowptr,
                                                  int* __restrict__ cursor, int n, int etot) {
    __shared__ int s[256];
    int t = threadIdx.x;
    int idx = blockIdx.x * 256 + t;
    int v = (idx < n) ? cnt[idx] : 0;
    s[t] = v;
    __syncthreads();
    for (int o = 1; o < 256; o <<= 1) {
        int add = (t >= o) ? s[t - o] : 0;
        __syncthreads();
        s[t] += add;
        __syncthreads();
    }
    if (idx < n) {
        int ex = bsumex[blockIdx.x] + s[t] - v;
        rowptr[idx] = ex;
        cursor[idx] = ex;
    }
    if (idx == 0) rowptr[n] = etot;
}

__global__ __launch_bounds__(256) void scatter_kernel(const int* __restrict__ dst,
                                                      const int* __restrict__ src,
                                                      int* __restrict__ cursor,
                                                      int* __restrict__ esrc, int e) {
    int stride = gridDim.x * 256;
    for (int i = blockIdx.x * 256 + threadIdx.x; i < e; i += stride) {
        int p = atomicAdd(&cursor[dst[i]], 1);
        esrc[p] = src[i];
    }
}

// =============== MFMA GEMM: qkv+skip — 2D grid, block 64 rows x 128 cols ======
// A[n x 128] bf16, Bt [896 x 128] bf16. 2x2 waves, wave = 32 rows x 64 cols.
// Output: col<256 q bf16 | col<512 k fp8 | col<768 v bf16 | else skip f32.
__global__ __launch_bounds__(256) void qkv_gemm(
    const u16* __restrict__ A, const u16* __restrict__ Bt,
    const float* __restrict__ bias, u16* __restrict__ qkv,
    float* __restrict__ skip, int n)
{
    int wid = threadIdx.x >> 6, lane = threadIdx.x & 63;
    int wr = wid >> 1, wc = wid & 1;
    int r0 = blockIdx.x * 64 + wr * 32;
    int c0 = blockIdx.y * 128 + wc * 64;
    int lm = lane & 15, quad = lane >> 4;

    // Last row-block reads overrun n into the adjacent ws buffer — harmless,
    // rows >= n are never stored.
    const u16* aBase = A  + (size_t)(r0 + lm) * 128 + quad * 8;
    const u16* bBase = Bt + (size_t)(c0 + lm) * 128 + quad * 8;

    f32x4 acc[2][4] = {};
#pragma unroll
    for (int kk = 0; kk < 128; kk += 32) {
        short8 a0 = *(const short8*)(aBase + kk);
        short8 a1 = *(const short8*)(aBase + 16 * 128 + kk);
#pragma unroll
        for (int j = 0; j < 4; ++j) {
            short8 bj = *(const short8*)(bBase + (size_t)j * 16 * 128 + kk);
            acc[0][j] = __builtin_amdgcn_mfma_f32_16x16x32_bf16(a0, bj, acc[0][j], 0, 0, 0);
            acc[1][j] = __builtin_amdgcn_mfma_f32_16x16x32_bf16(a1, bj, acc[1][j], 0, 0, 0);
        }
    }
    unsigned char* kout = (unsigned char*)qkv;
#pragma unroll
    for (int j = 0; j < 4; ++j) {
        int col = c0 + j * 16 + lm;
        float bv = bias[col];
#pragma unroll
        for (int rt = 0; rt < 2; ++rt) {
#pragma unroll
            for (int i2 = 0; i2 < 4; ++i2) {
                int row = r0 + rt * 16 + quad * 4 + i2;
                if (row >= n) continue;
                float v = acc[rt][j][i2] + bv;
                if (col < 256) {                       // q bf16
                    qkv[(size_t)row * 640 + col] = f2bf(v);
                } else if (col < 512) {                // k fp8 e4m3
                    int w = __builtin_amdgcn_cvt_pk_fp8_f32(v, v, 0, false);
                    kout[(size_t)row * 1280 + 512 + (col - 256)] = (unsigned char)(w & 0xff);
                } else if (col < 768) {                // v bf16
                    qkv[(size_t)row * 640 + (col - 128)] = f2bf(v);
                } else {                               // skip f32
                    skip[(size_t)row * 128 + (col - 768)] = v;
                }
            }
        }
    }
}

// =============== Attention: wave per dst, 2 edge slots, fp8 k ================
// Lane layout: slot=lane>>5, head=(lane>>4)&1, sub=lane&15. Lane owns 8 cols.
// Per-edge fetch: k 256 B (fp8) + v 512 B (bf16). Epilogue: slot merge +
// head-mean + skip + residual (sx in place) + LayerNorm2 -> y.
__global__ __launch_bounds__(256) void attn_kernel(
    const u16* __restrict__ qkv, const int* __restrict__ rowptr,
    const int* __restrict__ esrc, const float* __restrict__ x,
    float* __restrict__ sx, const float* __restrict__ g2,
    const float* __restrict__ b2, u16* __restrict__ y, int n)
{
    int wid = threadIdx.x >> 6, lane = threadIdx.x & 63;
    int i = blockIdx.x * 4 + wid;
    if (i >= n) return;
    int slot = lane >> 5;
    int sub  = lane & 15;
    int colOff = ((lane >> 4) & 1) * 128 + sub * 8;

    short8 q8 = *(const short8*)(qkv + (size_t)i * 640 + colOff);
    float qf[8];
#pragma unroll
    for (int j = 0; j < 8; ++j) qf[j] = bfe(q8, j);

    int beg = rowptr[i], end = rowptr[i + 1];
    float m = -INFINITY, l = 0.f;
    float acc[8] = {};
    const float scale = 0.08838834764831845f;   // 1/sqrt(128)

    int t = beg + slot;
    for (; t + 2 < end; t += 4) {               // 2 edges per slot in flight
        int s0 = esrc[t], s1 = esrc[t + 2];
        const u16* n0 = qkv + (size_t)s0 * 640;
        const u16* n1 = qkv + (size_t)s1 * 640;
        uint2 kw0 = *(const uint2*)((const unsigned char*)(n0 + 256) + colOff);
        uint2 kw1 = *(const uint2*)((const unsigned char*)(n1 + 256) + colOff);
        short8 v0 = *(const short8*)(n0 + 384 + colOff);
        short8 v1 = *(const short8*)(n1 + 384 + colOff);
        float k0f[8], k1f[8];
        fp8x4_to_f32((int)kw0.x, k0f); fp8x4_to_f32((int)kw0.y, k0f + 4);
        fp8x4_to_f32((int)kw1.x, k1f); fp8x4_to_f32((int)kw1.y, k1f + 4);
        float d0 = 0.f, d1 = 0.f;
#pragma unroll
        for (int j = 0; j < 8; ++j) {
            d0 += qf[j] * k0f[j];
            d1 += qf[j] * k1f[j];
        }
#pragma unroll
        for (int o = 1; o <= 8; o <<= 1) {      // reduce over 16-lane group
            d0 += __shfl_xor(d0, o);
            d1 += __shfl_xor(d1, o);
        }
        float al0 = d0 * scale, al1 = d1 * scale;
        float nm = fmaxf(m, fmaxf(al0, al1));
        float sc = expf(m - nm);                 // m=-inf first iter -> 0
        float w0 = expf(al0 - nm), w1 = expf(al1 - nm);
        l = l * sc + w0 + w1;
#pragma unroll
        for (int j = 0; j < 8; ++j)
            acc[j] = acc[j] * sc + w0 * bfe(v0, j) + w1 * bfe(v1, j);
        m = nm;
    }
    if (t < end) {                               // slot tail: single edge
        int s0 = esrc[t];
        const u16* n0 = qkv + (size_t)s0 * 640;
        uint2 kw0 = *(const uint2*)((const unsigned char*)(n0 + 256) + colOff);
        short8 v0 = *(const short8*)(n0 + 384 + colOff);
        float k0f[8];
        fp8x4_to_f32((int)kw0.x, k0f); fp8x4_to_f32((int)kw0.y, k0f + 4);
        float d0 = 0.f;
#pragma unroll
        for (int j = 0; j < 8; ++j) d0 += qf[j] * k0f[j];
#pragma unroll
        for (int o = 1; o <= 8; o <<= 1) d0 += __shfl_xor(d0, o);
        float al0 = d0 * scale;
        float nm = fmaxf(m, al0);
        float sc = expf(m - nm);
        float w0 = expf(al0 - nm);
        l = l * sc + w0;
#pragma unroll
        for (int j = 0; j < 8; ++j) acc[j] = acc[j] * sc + w0 * bfe(v0, j);
        m = nm;
    }

    // merge the two slots (guard exp(-inf - -inf) for degree<2 nodes)
    float mo = __shfl_xor(m, 32);
    float lo = __shfl_xor(l, 32);
    float nm = fmaxf(m, mo);
    float scS = (m  > -INFINITY) ? expf(m - nm)  : 0.f;
    float scO = (mo > -INFINITY) ? expf(mo - nm) : 0.f;
    l = l * scS + lo * scO;
    float inv = (l > 0.f) ? (1.f / l) : 0.f;
#pragma unroll
    for (int j = 0; j < 8; ++j) {
        float other = __shfl_xor(acc[j], 32);
        acc[j] = (acc[j] * scS + other * scO) * inv;
        acc[j] = 0.5f * (acc[j] + __shfl_xor(acc[j], 16));  // head mean
    }

    if (lane < 16) {                             // lanes 0..15 hold the row
        size_t base = (size_t)i * 128 + sub * 8;
        float4 xv0 = *(const float4*)(x + base);
        float4 xv1 = *(const float4*)(x + base + 4);
        float4 sk0 = *(const float4*)(sx + base);
        float4 sk1 = *(const float4*)(sx + base + 4);
        float r[8];
        r[0] = xv0.x + sk0.x + acc[0]; r[1] = xv0.y + sk0.y + acc[1];
        r[2] = xv0.z + sk0.z + acc[2]; r[3] = xv0.w + sk0.w + acc[3];
        r[4] = xv1.x + sk1.x + acc[4]; r[5] = xv1.y + sk1.y + acc[5];
        r[6] = xv1.z + sk1.z + acc[6]; r[7] = xv1.w + sk1.w + acc[7];
        *(float4*)(sx + base)     = make_float4(r[0], r[1], r[2], r[3]);
        *(float4*)(sx + base + 4) = make_float4(r[4], r[5], r[6], r[7]);
        float s1 = 0.f, s2 = 0.f;
#pragma unroll
        for (int j = 0; j < 8; ++j) { s1 += r[j]; s2 += r[j] * r[j]; }
#pragma unroll
        for (int o = 1; o <= 8; o <<= 1) {
            s1 += __shfl_xor(s1, o);
            s2 += __shfl_xor(s2, o);
        }
        float mu = s1 * (1.f / 128.f);
        float var = s2 * (1.f / 128.f) - mu * mu;
        float rstd = rsqrtf(var + 1e-5f);
        short8 o8;
#pragma unroll
        for (int j = 0; j < 8; ++j)
            o8[j] = (short)f2bf((r[j] - mu) * rstd * g2[sub * 8 + j] + b2[sub * 8 + j]);
        *(short8*)(y + base) = o8;
    }
}

// =============== Fused FFN: out = x2 + gelu(y2@W1T+b1)@W2T+b2 ===============
__global__ __launch_bounds__(256) void ffn_kernel(
    const u16* __restrict__ y2, const u16* __restrict__ W1T,
    const float* __restrict__ b1, const u16* __restrict__ W2T,
    const float* __restrict__ b2, const float* __restrict__ x2,
    float* __restrict__ out, int n)
{
    __shared__ u16 t1[64 * 136];
    int wid = threadIdx.x >> 6, lane = threadIdx.x & 63;
    int lm = lane & 15, quad = lane >> 4;
    int r0 = blockIdx.x * 64 + wid * 16;

    const u16* aBase = y2 + (size_t)(r0 + lm) * 128 + quad * 8;
    f32x4 acc[8] = {};
#pragma unroll
    for (int kk = 0; kk < 128; kk += 32) {
        short8 a0 = *(const short8*)(aBase + kk);
#pragma unroll
        for (int j = 0; j < 8; ++j) {
            short8 bj = *(const short8*)(W1T + (size_t)(j * 16 + lm) * 128 + quad * 8 + kk);
            acc[j] = __builtin_amdgcn_mfma_f32_16x16x32_bf16(a0, bj, acc[j], 0, 0, 0);
        }
    }
#pragma unroll
    for (int j = 0; j < 8; ++j) {
        int col = j * 16 + lm;
        float bv = b1[col];
#pragma unroll
        for (int i2 = 0; i2 < 4; ++i2) {
            int rl = wid * 16 + quad * 4 + i2;
            float v = acc[j][i2] + bv;
            v = 0.5f * v * (1.f + erff(v * 0.70710678118654752f));
            t1[rl * 136 + col] = f2bf(v);
        }
    }
    __syncthreads();

    f32x4 acc2[8] = {};
#pragma unroll
    for (int kk = 0; kk < 128; kk += 32) {
        short8 a0 = *(const short8*)(t1 + (wid * 16 + lm) * 136 + quad * 8 + kk);
#pragma unroll
        for (int j = 0; j < 8; ++j) {
            short8 bj = *(const short8*)(W2T + (size_t)(j * 16 + lm) * 128 + quad * 8 + kk);
            acc2[j] = __builtin_amdgcn_mfma_f32_16x16x32_bf16(a0, bj, acc2[j], 0, 0, 0);
        }
    }
#pragma unroll
    for (int j = 0; j < 8; ++j) {
        int col = j * 16 + lm;
        float bv = b2[col];
#pragma unroll
        for (int i2 = 0; i2 < 4; ++i2) {
            int row = r0 + quad * 4 + i2;
            if (row >= n) continue;
            size_t ob = (size_t)row * 128 + col;
            out[ob] = acc2[j][i2] + bv + x2[ob];
        }
    }
}

extern "C" void kernel_launch(void* const* d_in, const int* in_sizes, int n_in,
                              void* d_out, int out_size, void* d_ws, size_t ws_size,
                              hipStream_t stream)
{
    const float* x    = (const float*)d_in[0];
    const int*   ei   = (const int*)d_in[1];

    int n = in_sizes[0] / 128;     // 50000
    int e = in_sizes[1] / 2;       // 800000
    const int* src  = ei;          // edge_index[0] (messages src -> dst)
    const int* dstp = ei + e;      // edge_index[1]

    char* w = (char*)d_ws;
    size_t off = 0;
    auto alloc = [&](size_t bytes) -> void* {
        void* p = w + off;
        off = (off + bytes + 255) & ~(size_t)255;
        return p;
    };
    u16*   y    = (u16*)alloc((size_t)n * 128 * 2);   // LN1 out, then LN2 out
    u16*   qkv  = (u16*)alloc((size_t)n * 640 * 2);   // q bf16 | k fp8 | v bf16
    float* sx   = (float*)alloc((size_t)n * 128 * 4); // skip, then x2 in-place
    u16*   wt   = (u16*)alloc((size_t)147456 * 2);
    float* bc   = (float*)alloc(896 * 4);
    int* cnt    = (int*)alloc((size_t)n * 4);
    int* cursor = (int*)alloc((size_t)n * 4);
    int* rowptr = (int*)alloc(((size_t)n + 1) * 4);
    int* esrc   = (int*)alloc((size_t)e * 4);
    int* bsum   = (int*)alloc(1024);
    int* bsumex = (int*)alloc(1024);

    int gr  = (n + 63) / 64;       // row blocks (qkv + ffn)
    int nb  = (n + 255) / 256;     // scan chunks (196)

    fused_prep_ln<<<2048, 256, 0, stream>>>(
        x, (const float*)d_in[2], (const float*)d_in[3],
        (const float*)d_in[4], (const float*)d_in[6], (const float*)d_in[8],
        (const float*)d_in[10], (const float*)d_in[14], (const float*)d_in[16],
        (const float*)d_in[5], (const float*)d_in[7], (const float*)d_in[9],
        (const float*)d_in[11], wt, bc, y, cnt, n);
    hist_kernel<<<1024, 256, 0, stream>>>(dstp, cnt, e);
    scan_block_sum<<<nb, 256, 0, stream>>>(cnt, bsum, n);
    scan_partials<<<1, 256, 0, stream>>>(bsum, bsumex, nb);
    scan_write<<<nb, 256, 0, stream>>>(cnt, bsumex, rowptr, cursor, n, e);
    scatter_kernel<<<1024, 256, 0, stream>>>(dstp, src, cursor, esrc, e);
    qkv_gemm<<<dim3(gr, 7), 256, 0, stream>>>(y, wt, bc, qkv, sx, n);
    attn_kernel<<<(n + 3) / 4, 256, 0, stream>>>(qkv, rowptr, esrc, x, sx,
                                                 (const float*)d_in[12],
                                                 (const float*)d_in[13], y, n);
    ffn_kernel<<<gr, 256, 0, stream>>>(y, wt + 114688, (const float*)d_in[15],
                                       wt + 131072, (const float*)d_in[17],
                                       sx, (float*)d_out, n);
}

// Round 10
// 426.230 us; speedup vs baseline: 1.3476x; 1.0221x over previous
//
#include <hip/hip_runtime.h>
#include <hip/hip_bf16.h>
#include <math.h>

// EncoderLayer_68186900791439 — graph transformer encoder layer on MI355X.
// Round 10: qkv_gemm epilogue through LDS -> coalesced stores (r9: 97.8 us
// store-pipe-bound, 32 scattered 1-2 B stores/thread, WRITE 124 MB vs 90
// ideal). Tile 64x128 f32 staged in LDS, threads re-mapped row-major, 16 B
// stores only. Everything else identical to round 9.

typedef unsigned short u16;
using short8 = __attribute__((ext_vector_type(8))) short;
using f32x4  = __attribute__((ext_vector_type(4))) float;
using f32x2  = __attribute__((ext_vector_type(2))) float;

__device__ __forceinline__ float bf2f(u16 u) {
    return __uint_as_float(((unsigned int)u) << 16);
}
__device__ __forceinline__ u16 f2bf(float f) {
    __hip_bfloat16 h = __float2bfloat16(f);
    return __builtin_bit_cast(u16, h);
}
__device__ __forceinline__ float bfe(short8 v, int j) {
    return bf2f((u16)v[j]);
}
// decode 4 packed fp8-e4m3 (one dword) -> 4 f32 (HW cvt, OCP on gfx950)
__device__ __forceinline__ void fp8x4_to_f32(int w, float* out) {
    f32x2 lo = __builtin_amdgcn_cvt_pk_f32_fp8(w, false);
    f32x2 hi = __builtin_amdgcn_cvt_pk_f32_fp8(w, true);
    out[0] = lo[0]; out[1] = lo[1]; out[2] = hi[0]; out[3] = hi[1];
}
// pack 4 f32 -> 4 fp8-e4m3 bytes in one dword
__device__ __forceinline__ unsigned pack_fp8x4(float4 f) {
    unsigned w = 0;
    w = (unsigned)__builtin_amdgcn_cvt_pk_fp8_f32(f.x, f.y, (int)w, false);
    w = (unsigned)__builtin_amdgcn_cvt_pk_fp8_f32(f.z, f.w, (int)w, true);
    return w;
}

// ============ Kernel A: prep weights + bias concat + LN1 + zero cnt ==========
__global__ __launch_bounds__(256) void fused_prep_ln(
    const float* __restrict__ x, const float* __restrict__ ln1g,
    const float* __restrict__ ln1b,
    const float* __restrict__ Wq, const float* __restrict__ Wk,
    const float* __restrict__ Wv, const float* __restrict__ Ws,
    const float* __restrict__ W1, const float* __restrict__ W2,
    const float* __restrict__ bq, const float* __restrict__ bk,
    const float* __restrict__ bv, const float* __restrict__ bs,
    u16* __restrict__ wt, float* __restrict__ bc,
    u16* __restrict__ y, int* __restrict__ cnt, int n)
{
    int gsz = gridDim.x * 256;
    int gtid = blockIdx.x * 256 + threadIdx.x;

    for (int i = gtid; i < 147456 + 896; i += gsz) {
        if (i < 147456) {
            const float* W; int N; int base;
            if      (i <  32768) { W = Wq; N = 256; base = 0; }
            else if (i <  65536) { W = Wk; N = 256; base = 32768; }
            else if (i <  98304) { W = Wv; N = 256; base = 65536; }
            else if (i < 114688) { W = Ws; N = 128; base = 98304; }
            else if (i < 131072) { W = W1; N = 128; base = 114688; }
            else                 { W = W2; N = 128; base = 131072; }
            int j = i - base;
            int nIdx = j >> 7, k = j & 127;
            wt[i] = f2bf(W[(size_t)k * N + nIdx]);
        } else {
            int j = i - 147456;
            float v;
            if      (j < 256) v = bq[j];
            else if (j < 512) v = bk[j - 256];
            else if (j < 768) v = bv[j - 512];
            else              v = bs[j - 768];
            bc[j] = v;
        }
    }
    for (int i = gtid; i < n; i += gsz) cnt[i] = 0;
    int lane = threadIdx.x & 63;
    int gw = gtid >> 6, nw = gsz >> 6;
    for (int row = gw; row < n; row += nw) {
        size_t base = (size_t)row * 128;
        float v0 = x[base + lane];
        float v1 = x[base + 64 + lane];
        float s1 = v0 + v1, s2 = v0 * v0 + v1 * v1;
        for (int o = 1; o <= 32; o <<= 1) {
            s1 += __shfl_xor(s1, o);
            s2 += __shfl_xor(s2, o);
        }
        float mu = s1 * (1.f / 128.f);
        float var = s2 * (1.f / 128.f) - mu * mu;
        float rstd = rsqrtf(var + 1e-5f);
        y[base + lane]      = f2bf((v0 - mu) * rstd * ln1g[lane] + ln1b[lane]);
        y[base + 64 + lane] = f2bf((v1 - mu) * rstd * ln1g[64 + lane] + ln1b[64 + lane]);
    }
}

// ============================ CSR build ====================================
__global__ __launch_bounds__(256) void hist_kernel(const int* __restrict__ dst,
                                                   int* __restrict__ cnt, int e) {
    int stride = gridDim.x * 256;
    for (int i = blockIdx.x * 256 + threadIdx.x; i < e; i += stride)
        atomicAdd(&cnt[dst[i]], 1);
}

__global__ __launch_bounds__(256) void scan_block_sum(const int* __restrict__ cnt,
                                                      int* __restrict__ bsum, int n) {
    __shared__ int s[256];
    int idx = blockIdx.x * 256 + threadIdx.x;
    s[threadIdx.x] = (idx < n) ? cnt[idx] : 0;
    __syncthreads();
    for (int o = 128; o > 0; o >>= 1) {
        if (threadIdx.x < o) s[threadIdx.x] += s[threadIdx.x + o];
        __syncthreads();
    }
    if (threadIdx.x == 0) bsum[blockIdx.x] = s[0];
}
__global__ __launch_bounds__(256) void scan_partials(const int* __restrict__ bsum,
                                                     int* __restrict__ bsumex, int nb) {
    __shared__ int s[256];
    int t = threadIdx.x;
    int v = (t < nb) ? bsum[t] : 0;
    s[t] = v;
    __syncthreads();
    for (int o = 1; o < 256; o <<= 1) {
        int add = (t >= o) ? s[t - o] : 0;
        __syncthreads();
        s[t] += add;
        __syncthreads();
    }
    bsumex[t] = s[t] - v;
}
__global__ __launch_bounds__(256) void scan_write(const int* __restrict__ cnt,
                                                  const int* __restrict__ bsumex,
                                                  int* __restrict__ rowptr,
                                                  int* __restrict__ cursor, int n, int etot) {
    __shared__ int s[256];
    int t = threadIdx.x;
    int idx = blockIdx.x * 256 + t;
    int v = (idx < n) ? cnt[idx] : 0;
    s[t] = v;
    __syncthreads();
    for (int o = 1; o < 256; o <<= 1) {
        int add = (t >= o) ? s[t - o] : 0;
        __syncthreads();
        s[t] += add;
        __syncthreads();
    }
    if (idx < n) {
        int ex = bsumex[blockIdx.x] + s[t] - v;
        rowptr[idx] = ex;
        cursor[idx] = ex;
    }
    if (idx == 0) rowptr[n] = etot;
}

__global__ __launch_bounds__(256) void scatter_kernel(const int* __restrict__ dst,
                                                      const int* __restrict__ src,
                                                      int* __restrict__ cursor,
                                                      int* __restrict__ esrc, int e) {
    int stride = gridDim.x * 256;
    for (int i = blockIdx.x * 256 + threadIdx.x; i < e; i += stride) {
        int p = atomicAdd(&cursor[dst[i]], 1);
        esrc[p] = src[i];
    }
}

// =============== MFMA GEMM: qkv+skip — LDS epilogue, coalesced stores =========
// A[n x 128] bf16, Bt [896 x 128] bf16. Block 64 rows x 128 cols, 2x2 waves.
// Each col-block is a single output region (q / k-fp8 / v / skip), so the
// store branch is wave-uniform. Phase 1: MFMA -> LDS f32 tile (stride 132,
// 2-way bank alias = free). Phase 2: thread = (row, 32-col chunk) -> 16 B
// coalesced stores: q/v short8, k packed-fp8 uint4, skip float4.
__global__ __launch_bounds__(256) void qkv_gemm(
    const u16* __restrict__ A, const u16* __restrict__ Bt,
    const float* __restrict__ bias, u16* __restrict__ qkv,
    float* __restrict__ skip, int n)
{
    __shared__ float tile[64 * 132];                 // 33.8 KB
    int wid = threadIdx.x >> 6, lane = threadIdx.x & 63;
    int wr = wid >> 1, wc = wid & 1;
    int r0 = blockIdx.x * 64;
    int c0 = blockIdx.y * 128;
    int lm = lane & 15, quad = lane >> 4;

    // Last row-block reads overrun n into the adjacent ws buffer — harmless,
    // rows >= n are never stored.
    const u16* aBase = A  + (size_t)(r0 + wr * 32 + lm) * 128 + quad * 8;
    const u16* bBase = Bt + (size_t)(c0 + wc * 64 + lm) * 128 + quad * 8;

    f32x4 acc[2][4] = {};
#pragma unroll
    for (int kk = 0; kk < 128; kk += 32) {
        short8 a0 = *(const short8*)(aBase + kk);
        short8 a1 = *(const short8*)(aBase + 16 * 128 + kk);
#pragma unroll
        for (int j = 0; j < 4; ++j) {
            short8 bj = *(const short8*)(bBase + (size_t)j * 16 * 128 + kk);
            acc[0][j] = __builtin_amdgcn_mfma_f32_16x16x32_bf16(a0, bj, acc[0][j], 0, 0, 0);
            acc[1][j] = __builtin_amdgcn_mfma_f32_16x16x32_bf16(a1, bj, acc[1][j], 0, 0, 0);
        }
    }
    // phase 1: accumulators + bias -> LDS
#pragma unroll
    for (int j = 0; j < 4; ++j) {
        int colL = wc * 64 + j * 16 + lm;
        float bv = bias[c0 + colL];
#pragma unroll
        for (int rt = 0; rt < 2; ++rt) {
#pragma unroll
            for (int i2 = 0; i2 < 4; ++i2) {
                int rowL = wr * 32 + rt * 16 + quad * 4 + i2;
                tile[rowL * 132 + colL] = acc[rt][j][i2] + bv;
            }
        }
    }
    __syncthreads();

    // phase 2: coalesced stores, thread = (row, 32-col chunk)
    int rowL = threadIdx.x >> 2;
    int row  = r0 + rowL;
    if (row >= n) return;
    int ck = (threadIdx.x & 3) * 32;
    int cg = c0 + ck;
    float4 f[8];
#pragma unroll
    for (int k = 0; k < 8; ++k)
        f[k] = *(const float4*)&tile[rowL * 132 + ck + k * 4];

    if (c0 < 256) {                                   // q bf16
        u16* dst = qkv + (size_t)row * 640 + cg;
#pragma unroll
        for (int k = 0; k < 4; ++k) {
            short8 o;
            o[0] = (short)f2bf(f[2 * k].x);     o[1] = (short)f2bf(f[2 * k].y);
            o[2] = (short)f2bf(f[2 * k].z);     o[3] = (short)f2bf(f[2 * k].w);
            o[4] = (short)f2bf(f[2 * k + 1].x); o[5] = (short)f2bf(f[2 * k + 1].y);
            o[6] = (short)f2bf(f[2 * k + 1].z); o[7] = (short)f2bf(f[2 * k + 1].w);
            *(short8*)(dst + k * 8) = o;
        }
    } else if (c0 < 512) {                            // k fp8 e4m3, packed
        unsigned char* kb = (unsigned char*)qkv + (size_t)row * 1280 + 512 + (cg - 256);
        uint4 w0, w1;
        w0.x = pack_fp8x4(f[0]); w0.y = pack_fp8x4(f[1]);
        w0.z = pack_fp8x4(f[2]); w0.w = pack_fp8x4(f[3]);
        w1.x = pack_fp8x4(f[4]); w1.y = pack_fp8x4(f[5]);
        w1.z = pack_fp8x4(f[6]); w1.w = pack_fp8x4(f[7]);
        *(uint4*)kb = w0;
        *(uint4*)(kb + 16) = w1;
    } else if (c0 < 768) {                            // v bf16
        u16* dst = qkv + (size_t)row * 640 + (cg - 128);
#pragma unroll
        for (int k = 0; k < 4; ++k) {
            short8 o;
            o[0] = (short)f2bf(f[2 * k].x);     o[1] = (short)f2bf(f[2 * k].y);
            o[2] = (short)f2bf(f[2 * k].z);     o[3] = (short)f2bf(f[2 * k].w);
            o[4] = (short)f2bf(f[2 * k + 1].x); o[5] = (short)f2bf(f[2 * k + 1].y);
            o[6] = (short)f2bf(f[2 * k + 1].z); o[7] = (short)f2bf(f[2 * k + 1].w);
            *(short8*)(dst + k * 8) = o;
        }
    } else {                                          // skip f32
        float* dst = skip + (size_t)row * 128 + (cg - 768);
#pragma unroll
        for (int k = 0; k < 8; ++k)
            *(float4*)(dst + k * 4) = f[k];
    }
}

// =============== Attention: wave per dst, 2 edge slots, fp8 k ================
// Lane layout: slot=lane>>5, head=(lane>>4)&1, sub=lane&15. Lane owns 8 cols.
// Per-edge fetch: k 256 B (fp8) + v 512 B (bf16). Epilogue: slot merge +
// head-mean + skip + residual (sx in place) + LayerNorm2 -> y.
__global__ __launch_bounds__(256) void attn_kernel(
    const u16* __restrict__ qkv, const int* __restrict__ rowptr,
    const int* __restrict__ esrc, const float* __restrict__ x,
    float* __restrict__ sx, const float* __restrict__ g2,
    const float* __restrict__ b2, u16* __restrict__ y, int n)
{
    int wid = threadIdx.x >> 6, lane = threadIdx.x & 63;
    int i = blockIdx.x * 4 + wid;
    if (i >= n) return;
    int slot = lane >> 5;
    int sub  = lane & 15;
    int colOff = ((lane >> 4) & 1) * 128 + sub * 8;

    short8 q8 = *(const short8*)(qkv + (size_t)i * 640 + colOff);
    float qf[8];
#pragma unroll
    for (int j = 0; j < 8; ++j) qf[j] = bfe(q8, j);

    int beg = rowptr[i], end = rowptr[i + 1];
    float m = -INFINITY, l = 0.f;
    float acc[8] = {};
    const float scale = 0.08838834764831845f;   // 1/sqrt(128)

    int t = beg + slot;
    for (; t + 2 < end; t += 4) {               // 2 edges per slot in flight
        int s0 = esrc[t], s1 = esrc[t + 2];
        const u16* n0 = qkv + (size_t)s0 * 640;
        const u16* n1 = qkv + (size_t)s1 * 640;
        uint2 kw0 = *(const uint2*)((const unsigned char*)(n0 + 256) + colOff);
        uint2 kw1 = *(const uint2*)((const unsigned char*)(n1 + 256) + colOff);
        short8 v0 = *(const short8*)(n0 + 384 + colOff);
        short8 v1 = *(const short8*)(n1 + 384 + colOff);
        float k0f[8], k1f[8];
        fp8x4_to_f32((int)kw0.x, k0f); fp8x4_to_f32((int)kw0.y, k0f + 4);
        fp8x4_to_f32((int)kw1.x, k1f); fp8x4_to_f32((int)kw1.y, k1f + 4);
        float d0 = 0.f, d1 = 0.f;
#pragma unroll
        for (int j = 0; j < 8; ++j) {
            d0 += qf[j] * k0f[j];
            d1 += qf[j] * k1f[j];
        }
#pragma unroll
        for (int o = 1; o <= 8; o <<= 1) {      // reduce over 16-lane group
            d0 += __shfl_xor(d0, o);
            d1 += __shfl_xor(d1, o);
        }
        float al0 = d0 * scale, al1 = d1 * scale;
        float nm = fmaxf(m, fmaxf(al0, al1));
        float sc = expf(m - nm);                 // m=-inf first iter -> 0
        float w0 = expf(al0 - nm), w1 = expf(al1 - nm);
        l = l * sc + w0 + w1;
#pragma unroll
        for (int j = 0; j < 8; ++j)
            acc[j] = acc[j] * sc + w0 * bfe(v0, j) + w1 * bfe(v1, j);
        m = nm;
    }
    if (t < end) {                               // slot tail: single edge
        int s0 = esrc[t];
        const u16* n0 = qkv + (size_t)s0 * 640;
        uint2 kw0 = *(const uint2*)((const unsigned char*)(n0 + 256) + colOff);
        short8 v0 = *(const short8*)(n0 + 384 + colOff);
        float k0f[8];
        fp8x4_to_f32((int)kw0.x, k0f); fp8x4_to_f32((int)kw0.y, k0f + 4);
        float d0 = 0.f;
#pragma unroll
        for (int j = 0; j < 8; ++j) d0 += qf[j] * k0f[j];
#pragma unroll
        for (int o = 1; o <= 8; o <<= 1) d0 += __shfl_xor(d0, o);
        float al0 = d0 * scale;
        float nm = fmaxf(m, al0);
        float sc = expf(m - nm);
        float w0 = expf(al0 - nm);
        l = l * sc + w0;
#pragma unroll
        for (int j = 0; j < 8; ++j) acc[j] = acc[j] * sc + w0 * bfe(v0, j);
        m = nm;
    }

    // merge the two slots (guard exp(-inf - -inf) for degree<2 nodes)
    float mo = __shfl_xor(m, 32);
    float lo = __shfl_xor(l, 32);
    float nm = fmaxf(m, mo);
    float scS = (m  > -INFINITY) ? expf(m - nm)  : 0.f;
    float scO = (mo > -INFINITY) ? expf(mo - nm) : 0.f;
    l = l * scS + lo * scO;
    float inv = (l > 0.f) ? (1.f / l) : 0.f;
#pragma unroll
    for (int j = 0; j < 8; ++j) {
        float other = __shfl_xor(acc[j], 32);
        acc[j] = (acc[j] * scS + other * scO) * inv;
        acc[j] = 0.5f * (acc[j] + __shfl_xor(acc[j], 16));  // head mean
    }

    if (lane < 16) {                             // lanes 0..15 hold the row
        size_t base = (size_t)i * 128 + sub * 8;
        float4 xv0 = *(const float4*)(x + base);
        float4 xv1 = *(const float4*)(x + base + 4);
        float4 sk0 = *(const float4*)(sx + base);
        float4 sk1 = *(const float4*)(sx + base + 4);
        float r[8];
        r[0] = xv0.x + sk0.x + acc[0]; r[1] = xv0.y + sk0.y + acc[1];
        r[2] = xv0.z + sk0.z + acc[2]; r[3] = xv0.w + sk0.w + acc[3];
        r[4] = xv1.x + sk1.x + acc[4]; r[5] = xv1.y + sk1.y + acc[5];
        r[6] = xv1.z + sk1.z + acc[6]; r[7] = xv1.w + sk1.w + acc[7];
        *(float4*)(sx + base)     = make_float4(r[0], r[1], r[2], r[3]);
        *(float4*)(sx + base + 4) = make_float4(r[4], r[5], r[6], r[7]);
        float s1 = 0.f, s2 = 0.f;
#pragma unroll
        for (int j = 0; j < 8; ++j) { s1 += r[j]; s2 += r[j] * r[j]; }
#pragma unroll
        for (int o = 1; o <= 8; o <<= 1) {
            s1 += __shfl_xor(s1, o);
            s2 += __shfl_xor(s2, o);
        }
        float mu = s1 * (1.f / 128.f);
        float var = s2 * (1.f / 128.f) - mu * mu;
        float rstd = rsqrtf(var + 1e-5f);
        short8 o8;
#pragma unroll
        for (int j = 0; j < 8; ++j)
            o8[j] = (short)f2bf((r[j] - mu) * rstd * g2[sub * 8 + j] + b2[sub * 8 + j]);
        *(short8*)(y + base) = o8;
    }
}

// =============== Fused FFN: out = x2 + gelu(y2@W1T+b1)@W2T+b2 ===============
__global__ __launch_bounds__(256) void ffn_kernel(
    const u16* __restrict__ y2, const u16* __restrict__ W1T,
    const float* __restrict__ b1, const u16* __restrict__ W2T,
    const float* __restrict__ b2, const float* __restrict__ x2,
    float* __restrict__ out, int n)
{
    __shared__ u16 t1[64 * 136];
    int wid = threadIdx.x >> 6, lane = threadIdx.x & 63;
    int lm = lane & 15, quad = lane >> 4;
    int r0 = blockIdx.x * 64 + wid * 16;

    const u16* aBase = y2 + (size_t)(r0 + lm) * 128 + quad * 8;
    f32x4 acc[8] = {};
#pragma unroll
    for (int kk = 0; kk < 128; kk += 32) {
        short8 a0 = *(const short8*)(aBase + kk);
#pragma unroll
        for (int j = 0; j < 8; ++j) {
            short8 bj = *(const short8*)(W1T + (size_t)(j * 16 + lm) * 128 + quad * 8 + kk);
            acc[j] = __builtin_amdgcn_mfma_f32_16x16x32_bf16(a0, bj, acc[j], 0, 0, 0);
        }
    }
#pragma unroll
    for (int j = 0; j < 8; ++j) {
        int col = j * 16 + lm;
        float bv = b1[col];
#pragma unroll
        for (int i2 = 0; i2 < 4; ++i2) {
            int rl = wid * 16 + quad * 4 + i2;
            float v = acc[j][i2] + bv;
            v = 0.5f * v * (1.f + erff(v * 0.70710678118654752f));
            t1[rl * 136 + col] = f2bf(v);
        }
    }
    __syncthreads();

    f32x4 acc2[8] = {};
#pragma unroll
    for (int kk = 0; kk < 128; kk += 32) {
        short8 a0 = *(const short8*)(t1 + (wid * 16 + lm) * 136 + quad * 8 + kk);
#pragma unroll
        for (int j = 0; j < 8; ++j) {
            short8 bj = *(const short8*)(W2T + (size_t)(j * 16 + lm) * 128 + quad * 8 + kk);
            acc2[j] = __builtin_amdgcn_mfma_f32_16x16x32_bf16(a0, bj, acc2[j], 0, 0, 0);
        }
    }
#pragma unroll
    for (int j = 0; j < 8; ++j) {
        int col = j * 16 + lm;
        float bv = b2[col];
#pragma unroll
        for (int i2 = 0; i2 < 4; ++i2) {
            int row = r0 + quad * 4 + i2;
            if (row >= n) continue;
            size_t ob = (size_t)row * 128 + col;
            out[ob] = acc2[j][i2] + bv + x2[ob];
        }
    }
}

extern "C" void kernel_launch(void* const* d_in, const int* in_sizes, int n_in,
                              void* d_out, int out_size, void* d_ws, size_t ws_size,
                              hipStream_t stream)
{
    const float* x    = (const float*)d_in[0];
    const int*   ei   = (const int*)d_in[1];

    int n = in_sizes[0] / 128;     // 50000
    int e = in_sizes[1] / 2;       // 800000
    const int* src  = ei;          // edge_index[0] (messages src -> dst)
    const int* dstp = ei + e;      // edge_index[1]

    char* w = (char*)d_ws;
    size_t off = 0;
    auto alloc = [&](size_t bytes) -> void* {
        void* p = w + off;
        off = (off + bytes + 255) & ~(size_t)255;
        return p;
    };
    u16*   y    = (u16*)alloc((size_t)n * 128 * 2);   // LN1 out, then LN2 out
    u16*   qkv  = (u16*)alloc((size_t)n * 640 * 2);   // q bf16 | k fp8 | v bf16
    float* sx   = (float*)alloc((size_t)n * 128 * 4); // skip, then x2 in-place
    u16*   wt   = (u16*)alloc((size_t)147456 * 2);
    float* bc   = (float*)alloc(896 * 4);
    int* cnt    = (int*)alloc((size_t)n * 4);
    int* cursor = (int*)alloc((size_t)n * 4);
    int* rowptr = (int*)alloc(((size_t)n + 1) * 4);
    int* esrc   = (int*)alloc((size_t)e * 4);
    int* bsum   = (int*)alloc(1024);
    int* bsumex = (int*)alloc(1024);

    int gr  = (n + 63) / 64;       // row blocks (qkv + ffn)
    int nb  = (n + 255) / 256;     // scan chunks (196)

    fused_prep_ln<<<2048, 256, 0, stream>>>(
        x, (const float*)d_in[2], (const float*)d_in[3],
        (const float*)d_in[4], (const float*)d_in[6], (const float*)d_in[8],
        (const float*)d_in[10], (const float*)d_in[14], (const float*)d_in[16],
        (const float*)d_in[5], (const float*)d_in[7], (const float*)d_in[9],
        (const float*)d_in[11], wt, bc, y, cnt, n);
    hist_kernel<<<1024, 256, 0, stream>>>(dstp, cnt, e);
    scan_block_sum<<<nb, 256, 0, stream>>>(cnt, bsum, n);
    scan_partials<<<1, 256, 0, stream>>>(bsum, bsumex, nb);
    scan_write<<<nb, 256, 0, stream>>>(cnt, bsumex, rowptr, cursor, n, e);
    scatter_kernel<<<1024, 256, 0, stream>>>(dstp, src, cursor, esrc, e);
    qkv_gemm<<<dim3(gr, 7), 256, 0, stream>>>(y, wt, bc, qkv, sx, n);
    attn_kernel<<<(n + 3) / 4, 256, 0, stream>>>(qkv, rowptr, esrc, x, sx,
                                                 (const float*)d_in[12],
                                                 (const float*)d_in[13], y, n);
    ffn_kernel<<<gr, 256, 0, stream>>>(y, wt + 114688, (const float*)d_in[15],
                                       wt + 131072, (const float*)d_in[17],
                                       sx, (float*)d_out, n);
}